// Round 11
// baseline (247.396 us; speedup 1.0000x reference)
//
#include <hip/hip_runtime.h>

#define N_NODES 100000
#define N_EDGES 1200000
#define BK 128                    // nodes per bucket
#define NB 782                    // ceil(100000/128)
#define CHUNK_E 4096
#define NBLK_E 293                // ceil(N_EDGES / CHUNK_E)
#define TOT_H (NB * NBLK_E)       // 229126
#define NSB2 ((TOT_H + 1023) / 1024)   // 224
#define CAP 4096                  // LDS edge-list capacity (expected ~1535 +- 39)

// Workspace layout (bytes), ~50.2 MB (d_ws is 256 MiB per harness poison):
#define OFF_ROWPTR 0
#define OFF_HISTG  400896
#define OFF_HSCAN  1317632
#define OFF_BLK2   2234368
#define OFF_PAIRS  2235392
#define OFF_SORTED 7035392
#define OFF_Y1     11835392
#define OFF_H1     24635392

__device__ __forceinline__ unsigned short f2bf(float f) {
    unsigned u = __float_as_uint(f);
    unsigned r = (u + 0x7fffu + ((u >> 16) & 1u)) >> 16;   // RNE
    return (unsigned short)r;
}

// ---- bucket-grouped pair build (atomic-free radix pass) ----

__global__ __launch_bounds__(256) void chunk_hist_kernel(
    const int* __restrict__ dst, int* __restrict__ hist_g)
{
    __shared__ int h[NB];
    const int e0 = blockIdx.x * CHUNK_E;
    const int e1 = min(e0 + CHUNK_E, N_EDGES);
    for (int i = threadIdx.x; i < NB; i += 256) h[i] = 0;
    __syncthreads();
    for (int e = e0 + threadIdx.x; e < e1; e += 256)
        atomicAdd(&h[dst[e] >> 7], 1);
    __syncthreads();
    for (int i = threadIdx.x; i < NB; i += 256)
        hist_g[i * NBLK_E + blockIdx.x] = h[i];
}

__global__ __launch_bounds__(1024) void scan2_blocks_kernel(
    const int* __restrict__ hist_g, int* __restrict__ hs_scan, int* __restrict__ blk2)
{
    __shared__ int s[1024];
    int i = blockIdx.x * 1024 + threadIdx.x;
    int v = (i < TOT_H) ? hist_g[i] : 0;
    s[threadIdx.x] = v;
    __syncthreads();
    for (int off = 1; off < 1024; off <<= 1) {
        int t = (threadIdx.x >= off) ? s[threadIdx.x - off] : 0;
        __syncthreads();
        s[threadIdx.x] += t;
        __syncthreads();
    }
    if (i < TOT_H) hs_scan[i] = s[threadIdx.x] - v;
    if (threadIdx.x == 1023) blk2[blockIdx.x] = s[1023];
}

__global__ __launch_bounds__(256) void scan2_tops_kernel(int* __restrict__ blk2)
{
    __shared__ int s[256];
    int v = (threadIdx.x < NSB2) ? blk2[threadIdx.x] : 0;
    s[threadIdx.x] = v;
    __syncthreads();
    for (int off = 1; off < 256; off <<= 1) {
        int t = (threadIdx.x >= off) ? s[threadIdx.x - off] : 0;
        __syncthreads();
        s[threadIdx.x] += t;
        __syncthreads();
    }
    if (threadIdx.x < NSB2) blk2[threadIdx.x] = s[threadIdx.x] - v;  // exclusive
}

__global__ __launch_bounds__(256) void pair_scatter_kernel(
    const int* __restrict__ src, const int* __restrict__ dst,
    const int* __restrict__ hs_scan, const int* __restrict__ blk2,
    unsigned* __restrict__ pairs)
{
    __shared__ int base_s[NB];
    __shared__ int cur_s[NB];
    const int b = blockIdx.x;
    const int e0 = b * CHUNK_E;
    const int e1 = min(e0 + CHUNK_E, N_EDGES);

    for (int i = threadIdx.x; i < NB; i += 256) {
        int idx = i * NBLK_E + b;
        base_s[i] = hs_scan[idx] + blk2[idx >> 10];
        cur_s[i] = 0;
    }
    __syncthreads();
    for (int e = e0 + threadIdx.x; e < e1; e += 256) {
        int d = dst[e];
        int bk = d >> 7;
        int pos = base_s[bk] + atomicAdd(&cur_s[bk], 1);
        pairs[pos] = ((unsigned)src[e] << 7) | (unsigned)(d & 127);
    }
}

// ---- Dense transforms (weights-in-lanes, nodes streamed through LDS) ----

__global__ __launch_bounds__(256) void dense1_kernel(
    const float* __restrict__ x,
    const float* __restrict__ Wn, const float* __restrict__ Ws,
    const float* __restrict__ b,
    unsigned short* __restrict__ y1, float* __restrict__ z1)
{
    __shared__ float sx[32 * 64];
    const int t = threadIdx.x;
    const int w = t >> 6;
    const int lane = t & 63;
    const int half = w >> 1;
    const int nsub = (w & 1) * 16;
    const int chunk = blockIdx.x * 32;

    {
        const float4* gx = (const float4*)(x + (size_t)chunk * 64);
        float4* sx4 = (float4*)sx;
        sx4[t] = gx[t];
        sx4[t + 256] = gx[t + 256];
    }

    const float* W = half ? Ws : Wn;
    float wr[64];
#pragma unroll
    for (int k = 0; k < 64; ++k) wr[k] = W[k * 64 + lane];
    const float bj = half ? b[lane] : 0.f;

    __syncthreads();

#pragma unroll 1
    for (int m = 0; m < 16; ++m) {
        const int node = nsub + m;
        const float4* xr = (const float4*)(sx + node * 64);
        float a0 = 0.f, a1 = 0.f, a2 = 0.f, a3 = 0.f;
#pragma unroll
        for (int k4 = 0; k4 < 16; ++k4) {
            float4 v = xr[k4];
            a0 += v.x * wr[4 * k4 + 0];
            a1 += v.y * wr[4 * k4 + 1];
            a2 += v.z * wr[4 * k4 + 2];
            a3 += v.w * wr[4 * k4 + 3];
        }
        const float o = (a0 + a1) + (a2 + a3) + bj;
        const size_t gn = (size_t)(chunk + node);
        if (half) z1[gn * 64 + lane] = o;
        else      y1[gn * 64 + lane] = f2bf(o);
    }
}

__global__ __launch_bounds__(256) void dense2_kernel(
    const float* __restrict__ h1,
    const float* __restrict__ Wn, const float* __restrict__ Ws,
    const float* __restrict__ b,
    float* __restrict__ y2, float* __restrict__ out)
{
    __shared__ float sx[32 * 68];
    const int t = threadIdx.x;
    const int w = t >> 6;
    const int lane = t & 63;
    const int half = w >> 1;
    const int nsub = (w & 1) * 16;
    const int j = lane & 15;
    const int g = lane >> 4;
    const int chunk = blockIdx.x * 32;

    {
        const float4* gx = (const float4*)(h1 + (size_t)chunk * 64);
        float4* sx4 = (float4*)sx;
        int r0 = t >> 4, c0 = t & 15;
        sx4[r0 * 17 + c0] = gx[t];
        sx4[(r0 + 16) * 17 + c0] = gx[t + 256];
    }

    const float* W = half ? Ws : Wn;
    float wr[64];
#pragma unroll
    for (int k = 0; k < 64; ++k) wr[k] = W[k * 16 + j];
    const float bj = half ? b[j] : 0.f;

    __syncthreads();

#pragma unroll 1
    for (int q = 0; q < 4; ++q) {
        const int node = nsub + q * 4 + g;
        const float4* xr = (const float4*)(sx + node * 68);
        float a0 = 0.f, a1 = 0.f, a2 = 0.f, a3 = 0.f;
#pragma unroll
        for (int k4 = 0; k4 < 16; ++k4) {
            float4 v = xr[k4];
            a0 += v.x * wr[4 * k4 + 0];
            a1 += v.y * wr[4 * k4 + 1];
            a2 += v.z * wr[4 * k4 + 2];
            a3 += v.w * wr[4 * k4 + 3];
        }
        const float o = (a0 + a1) + (a2 + a3) + bj;
        const size_t gn = (size_t)(chunk + node);
        if (half) out[gn * 16 + j] = o;
        else      y2[gn * 16 + j] = o;
    }
}

// ---- Fused bucket sort + gather1 ----
// One block per 128-node bucket: build per-node sorted edge list in LDS,
// stream it out (sorted_src/row_ptr for gather2), then gather y1 rows with
// edge ids read from LDS. h1[n] = relu(z1[n] + mean(y1[src])).
__global__ __launch_bounds__(512) void fused_gather1_kernel(
    const unsigned short* __restrict__ y1,
    const unsigned* __restrict__ pairs,
    const int* __restrict__ hs_scan, const int* __restrict__ blk2,
    int* __restrict__ row_ptr, int* __restrict__ sorted_src,
    float* __restrict__ h1)
{
    __shared__ int slist[CAP];
    __shared__ int hist[BK];
    __shared__ int sc[BK];
    __shared__ int cur[BK];
    const int b = blockIdx.x;
    const int t = threadIdx.x;
    const int lane = t & 63;
    const int wv = t >> 6;            // 0..7
    const int g = lane >> 3;          // 8 edge slots
    const int fl = lane & 7;          // uint4 chunk of the 128 B row

    const int i0 = b * NBLK_E;
    const int start = hs_scan[i0] + blk2[i0 >> 10];
    const int end = (b == NB - 1) ? N_EDGES
                    : hs_scan[i0 + NBLK_E] + blk2[(i0 + NBLK_E) >> 10];
    const int cnt = end - start;
    const int node0 = b * BK;

    if (t < BK) hist[t] = 0;
    __syncthreads();
    for (int e = start + t; e < end; e += 512)
        atomicAdd(&hist[pairs[e] & 127u], 1);
    __syncthreads();

    // exclusive scan of 128 counts (guarded Hillis-Steele, full-block barriers)
    int v = (t < BK) ? hist[t] : 0;
    if (t < BK) sc[t] = v;
    __syncthreads();
    for (int off = 1; off < BK; off <<= 1) {
        int tv = (t >= off && t < BK) ? sc[t - off] : 0;
        __syncthreads();
        if (t < BK) sc[t] += tv;
        __syncthreads();
    }
    const int excl = (t < BK) ? sc[t] - v : 0;
    if (t < BK && node0 + t < N_NODES) row_ptr[node0 + t] = start + excl;
    if (b == NB - 1 && t == 0) row_ptr[N_NODES] = N_EDGES;
    if (t < BK) cur[t] = excl;        // slice-local cursors
    __syncthreads();

    if (cnt <= CAP) {
        // build LDS sorted list
        for (int e = start + t; e < end; e += 512) {
            unsigned u = pairs[e];
            int p = atomicAdd(&cur[u & 127u], 1);
            slist[p] = (int)(u >> 7);
        }
        __syncthreads();
        // stream out for gather2 (coalesced)
        for (int i = t; i < cnt; i += 512)
            sorted_src[start + i] = slist[i];
        // gather: wave wv owns nodes wv*16 .. wv*16+15
        for (int m = 0; m < 16; ++m) {
            const int node = wv * 16 + m;
            const int gn = node0 + node;
            if (gn >= N_NODES) break;
            const int o = sc[node] - hist[node];
            const int dg = hist[node];
            float a0 = 0.f, a1 = 0.f, a2 = 0.f, a3 = 0.f;
            float a4 = 0.f, a5 = 0.f, a6 = 0.f, a7 = 0.f;
            for (int base = 0; base < dg; base += 8) {
                const int idx = base + g;
                if (idx < dg) {
                    const int s = slist[o + idx];
                    uint4 raw = ((const uint4*)(y1 + (size_t)s * 64))[fl];
                    a0 += __uint_as_float(raw.x << 16);
                    a1 += __uint_as_float(raw.x & 0xffff0000u);
                    a2 += __uint_as_float(raw.y << 16);
                    a3 += __uint_as_float(raw.y & 0xffff0000u);
                    a4 += __uint_as_float(raw.z << 16);
                    a5 += __uint_as_float(raw.z & 0xffff0000u);
                    a6 += __uint_as_float(raw.w << 16);
                    a7 += __uint_as_float(raw.w & 0xffff0000u);
                }
            }
#pragma unroll
            for (int d = 8; d <= 32; d <<= 1) {
                a0 += __shfl_xor(a0, d); a1 += __shfl_xor(a1, d);
                a2 += __shfl_xor(a2, d); a3 += __shfl_xor(a3, d);
                a4 += __shfl_xor(a4, d); a5 += __shfl_xor(a5, d);
                a6 += __shfl_xor(a6, d); a7 += __shfl_xor(a7, d);
            }
            const float invd = 1.0f / (float)max(dg, 1);
            if (g == 0) {
                float4* hp = (float4*)(h1 + (size_t)gn * 64);
                float4 z0 = hp[fl * 2];
                float4 z1v = hp[fl * 2 + 1];
                hp[fl * 2] = make_float4(fmaxf(z0.x + a0 * invd, 0.f),
                                         fmaxf(z0.y + a1 * invd, 0.f),
                                         fmaxf(z0.z + a2 * invd, 0.f),
                                         fmaxf(z0.w + a3 * invd, 0.f));
                hp[fl * 2 + 1] = make_float4(fmaxf(z1v.x + a4 * invd, 0.f),
                                             fmaxf(z1v.y + a5 * invd, 0.f),
                                             fmaxf(z1v.z + a6 * invd, 0.f),
                                             fmaxf(z1v.w + a7 * invd, 0.f));
            }
        }
    } else {
        // fallback (statistically unreachable): global two-phase sort + gather
        if (t < BK) cur[t] = start + excl;
        __syncthreads();
        for (int e = start + t; e < end; e += 512) {
            unsigned u = pairs[e];
            int p = atomicAdd(&cur[u & 127u], 1);
            sorted_src[p] = (int)(u >> 7);
        }
        __syncthreads();
        for (int m = 0; m < 16; ++m) {
            const int node = wv * 16 + m;
            const int gn = node0 + node;
            if (gn >= N_NODES) break;
            const int o = start + sc[node] - hist[node];
            const int dg = hist[node];
            float a0 = 0.f, a1 = 0.f, a2 = 0.f, a3 = 0.f;
            float a4 = 0.f, a5 = 0.f, a6 = 0.f, a7 = 0.f;
            for (int base = 0; base < dg; base += 8) {
                const int idx = base + g;
                if (idx < dg) {
                    const int s = sorted_src[o + idx];
                    uint4 raw = ((const uint4*)(y1 + (size_t)s * 64))[fl];
                    a0 += __uint_as_float(raw.x << 16);
                    a1 += __uint_as_float(raw.x & 0xffff0000u);
                    a2 += __uint_as_float(raw.y << 16);
                    a3 += __uint_as_float(raw.y & 0xffff0000u);
                    a4 += __uint_as_float(raw.z << 16);
                    a5 += __uint_as_float(raw.z & 0xffff0000u);
                    a6 += __uint_as_float(raw.w << 16);
                    a7 += __uint_as_float(raw.w & 0xffff0000u);
                }
            }
#pragma unroll
            for (int d = 8; d <= 32; d <<= 1) {
                a0 += __shfl_xor(a0, d); a1 += __shfl_xor(a1, d);
                a2 += __shfl_xor(a2, d); a3 += __shfl_xor(a3, d);
                a4 += __shfl_xor(a4, d); a5 += __shfl_xor(a5, d);
                a6 += __shfl_xor(a6, d); a7 += __shfl_xor(a7, d);
            }
            const float invd = 1.0f / (float)max(dg, 1);
            if (g == 0) {
                float4* hp = (float4*)(h1 + (size_t)gn * 64);
                float4 z0 = hp[fl * 2];
                float4 z1v = hp[fl * 2 + 1];
                hp[fl * 2] = make_float4(fmaxf(z0.x + a0 * invd, 0.f),
                                         fmaxf(z0.y + a1 * invd, 0.f),
                                         fmaxf(z0.z + a2 * invd, 0.f),
                                         fmaxf(z0.w + a3 * invd, 0.f));
                hp[fl * 2 + 1] = make_float4(fmaxf(z1v.x + a4 * invd, 0.f),
                                             fmaxf(z1v.y + a5 * invd, 0.f),
                                             fmaxf(z1v.z + a6 * invd, 0.f),
                                             fmaxf(z1v.w + a7 * invd, 0.f));
            }
        }
    }
}

// out[n] += mean(y2[src]); 16 edges in flight, float4 per lane.
__global__ __launch_bounds__(256) void gather2_kernel(
    const float* __restrict__ y2,
    const int* __restrict__ row_ptr,
    const int* __restrict__ sorted_src,
    float* __restrict__ out)
{
    const int w = threadIdx.x >> 6;
    const int lane = threadIdx.x & 63;
    const int n = blockIdx.x * 4 + w;
    const int group = lane >> 2;
    const int fl = lane & 3;

    const int start = row_ptr[n];
    const int deg = row_ptr[n + 1] - start;

    float4 acc = make_float4(0.f, 0.f, 0.f, 0.f);
    for (int base = 0; base < deg; base += 64) {
        const int m = min(64, deg - base);
        int eid = 0;
        if (lane < m) eid = sorted_src[start + base + lane];
        for (int jj = 0; jj < m; jj += 16) {
            const int idx = jj + group;
            const int s = __shfl(eid, idx);
            if (idx < m) {
                float4 v = ((const float4*)(y2 + (size_t)s * 16))[fl];
                acc.x += v.x; acc.y += v.y; acc.z += v.z; acc.w += v.w;
            }
        }
    }
#pragma unroll
    for (int d = 4; d <= 32; d <<= 1) {
        acc.x += __shfl_xor(acc.x, d); acc.y += __shfl_xor(acc.y, d);
        acc.z += __shfl_xor(acc.z, d); acc.w += __shfl_xor(acc.w, d);
    }
    const float invd = 1.0f / (float)max(deg, 1);
    if (lane < 4) {
        float4* op = (float4*)(out + (size_t)n * 16);
        float4 z = op[fl];
        op[fl] = make_float4(z.x + acc.x * invd, z.y + acc.y * invd,
                             z.z + acc.z * invd, z.w + acc.w * invd);
    }
}

extern "C" void kernel_launch(void* const* d_in, const int* in_sizes, int n_in,
                              void* d_out, int out_size, void* d_ws, size_t ws_size,
                              hipStream_t stream) {
    const float* x   = (const float*)d_in[0];
    const int*   src = (const int*)d_in[1];
    const int*   dst = (const int*)d_in[2];
    const float* W1s = (const float*)d_in[3];
    const float* W1n = (const float*)d_in[4];
    const float* b1  = (const float*)d_in[5];
    const float* W2s = (const float*)d_in[6];
    const float* W2n = (const float*)d_in[7];
    const float* b2  = (const float*)d_in[8];
    float* out = (float*)d_out;

    char* ws = (char*)d_ws;
    int* row_ptr    = (int*)(ws + OFF_ROWPTR);
    int* hist_g     = (int*)(ws + OFF_HISTG);
    int* hs_scan    = (int*)(ws + OFF_HSCAN);
    int* blk2       = (int*)(ws + OFF_BLK2);
    unsigned* pairs = (unsigned*)(ws + OFF_PAIRS);
    int* sorted_src = (int*)(ws + OFF_SORTED);
    unsigned short* y1 = (unsigned short*)(ws + OFF_Y1);
    float* y2       = (float*)(ws + OFF_Y1);   // reuses y1 space after fused_gather1
    float* h1       = (float*)(ws + OFF_H1);

    // bucket-grouped pair build (zero global atomics)
    chunk_hist_kernel<<<NBLK_E, 256, 0, stream>>>(dst, hist_g);
    scan2_blocks_kernel<<<NSB2, 1024, 0, stream>>>(hist_g, hs_scan, blk2);
    scan2_tops_kernel<<<1, 256, 0, stream>>>(blk2);
    pair_scatter_kernel<<<NBLK_E, 256, 0, stream>>>(src, dst, hs_scan, blk2, pairs);

    // Layer 1 (fused sort+gather; also emits row_ptr/sorted_src for layer 2)
    dense1_kernel<<<3125, 256, 0, stream>>>(x, W1n, W1s, b1, y1, h1);
    fused_gather1_kernel<<<NB, 512, 0, stream>>>(y1, pairs, hs_scan, blk2,
                                                 row_ptr, sorted_src, h1);

    // Layer 2
    dense2_kernel<<<3125, 256, 0, stream>>>(h1, W2n, W2s, b2, y2, out);
    gather2_kernel<<<N_NODES / 4, 256, 0, stream>>>(y2, row_ptr, sorted_src, out);
}

// Round 12
// 240.887 us; speedup vs baseline: 1.0270x; 1.0270x over previous
//
#include <hip/hip_runtime.h>

#define N_NODES 100000
#define N_EDGES 1200000
#define BK 128                    // nodes per bucket
#define NB 782                    // ceil(100000/128)
#define CHUNK_E 4096
#define NBLK_E 293                // ceil(N_EDGES / CHUNK_E)
#define TOT_H (NB * NBLK_E)       // 229126
#define NSB2 ((TOT_H + 1023) / 1024)   // 224
#define CAP 4096                  // LDS edge-list capacity (expected ~1535 +- 39)
#define ND1 3125                  // dense1 blocks (32 nodes each)

// Workspace layout (bytes), ~50.2 MB:
#define OFF_ROWPTR 0
#define OFF_HISTG  400896
#define OFF_HSCAN  1317632
#define OFF_BLK2   2234368
#define OFF_PAIRS  2235392
#define OFF_SORTED 7035392
#define OFF_Y1     11835392
#define OFF_H1     24635392

__device__ __forceinline__ unsigned short f2bf(float f) {
    unsigned u = __float_as_uint(f);
    unsigned r = (u + 0x7fffu + ((u >> 16) & 1u)) >> 16;   // RNE
    return (unsigned short)r;
}

// ---- K1: chunk_hist (blocks 0..292) + dense1 (blocks 293..3417) fused ----
// Independent work co-scheduled in one launch: dense1 overlaps the CSR hist.
__global__ __launch_bounds__(256) void hist_dense1_kernel(
    const int* __restrict__ dst, int* __restrict__ hist_g,
    const float* __restrict__ x,
    const float* __restrict__ Wn, const float* __restrict__ Ws,
    const float* __restrict__ b,
    unsigned short* __restrict__ y1, float* __restrict__ z1)
{
    __shared__ float sx[32 * 64];   // 8 KB; hist part reuses as int h[NB]
    const int t = threadIdx.x;

    if (blockIdx.x < NBLK_E) {
        // ---- chunk_hist ----
        int* h = (int*)sx;
        const int e0 = blockIdx.x * CHUNK_E;
        const int e1 = min(e0 + CHUNK_E, N_EDGES);
        for (int i = t; i < NB; i += 256) h[i] = 0;
        __syncthreads();
        for (int e = e0 + t; e < e1; e += 256)
            atomicAdd(&h[dst[e] >> 7], 1);
        __syncthreads();
        for (int i = t; i < NB; i += 256)
            hist_g[i * NBLK_E + blockIdx.x] = h[i];
        return;
    }

    // ---- dense1 ----
    const int bid = blockIdx.x - NBLK_E;
    const int w = t >> 6;
    const int lane = t & 63;
    const int half = w >> 1;
    const int nsub = (w & 1) * 16;
    const int chunk = bid * 32;

    {
        const float4* gx = (const float4*)(x + (size_t)chunk * 64);
        float4* sx4 = (float4*)sx;
        sx4[t] = gx[t];
        sx4[t + 256] = gx[t + 256];
    }

    const float* W = half ? Ws : Wn;
    float wr[64];
#pragma unroll
    for (int k = 0; k < 64; ++k) wr[k] = W[k * 64 + lane];
    const float bj = half ? b[lane] : 0.f;

    __syncthreads();

#pragma unroll 1
    for (int m = 0; m < 16; ++m) {
        const int node = nsub + m;
        const float4* xr = (const float4*)(sx + node * 64);
        float a0 = 0.f, a1 = 0.f, a2 = 0.f, a3 = 0.f;
#pragma unroll
        for (int k4 = 0; k4 < 16; ++k4) {
            float4 v = xr[k4];
            a0 += v.x * wr[4 * k4 + 0];
            a1 += v.y * wr[4 * k4 + 1];
            a2 += v.z * wr[4 * k4 + 2];
            a3 += v.w * wr[4 * k4 + 3];
        }
        const float o = (a0 + a1) + (a2 + a3) + bj;
        const size_t gn = (size_t)(chunk + node);
        if (half) z1[gn * 64 + lane] = o;
        else      y1[gn * 64 + lane] = f2bf(o);
    }
}

// ---- K2: block-local scan of hist_g; blk2 holds RAW block sums ----
__global__ __launch_bounds__(1024) void scan2_blocks_kernel(
    const int* __restrict__ hist_g, int* __restrict__ hs_scan, int* __restrict__ blk2)
{
    __shared__ int s[1024];
    int i = blockIdx.x * 1024 + threadIdx.x;
    int v = (i < TOT_H) ? hist_g[i] : 0;
    s[threadIdx.x] = v;
    __syncthreads();
    for (int off = 1; off < 1024; off <<= 1) {
        int t = (threadIdx.x >= off) ? s[threadIdx.x - off] : 0;
        __syncthreads();
        s[threadIdx.x] += t;
        __syncthreads();
    }
    if (i < TOT_H) hs_scan[i] = s[threadIdx.x] - v;
    if (threadIdx.x == 1023) blk2[blockIdx.x] = s[1023];
}

// local exclusive scan of blk2 (NSB2<=256) into tops[]; call with >=256 threads
__device__ __forceinline__ void local_tops_scan(const int* blk2, int* tops, int t)
{
    if (t < 256) {
        int v = (t < NSB2) ? blk2[t] : 0;
        tops[t] = v;
    }
    __syncthreads();
    for (int off = 1; off < 256; off <<= 1) {
        int tv = (t >= off && t < 256) ? tops[t - off] : 0;
        __syncthreads();
        if (t < 256) tops[t] += tv;
        __syncthreads();
    }
    // convert inclusive -> exclusive
    int ex = 0;
    if (t < 256) ex = tops[t] - ((t < NSB2) ? blk2[t] : 0);
    __syncthreads();
    if (t < 256) tops[t] = ex;
    __syncthreads();
}

// ---- K3: deterministic pair scatter (tops re-derived locally) ----
__global__ __launch_bounds__(256) void pair_scatter_kernel(
    const int* __restrict__ src, const int* __restrict__ dst,
    const int* __restrict__ hs_scan, const int* __restrict__ blk2,
    unsigned* __restrict__ pairs)
{
    __shared__ int base_s[NB];
    __shared__ int cur_s[NB];
    __shared__ int tops[256];
    const int b = blockIdx.x;
    const int t = threadIdx.x;
    const int e0 = b * CHUNK_E;
    const int e1 = min(e0 + CHUNK_E, N_EDGES);

    local_tops_scan(blk2, tops, t);

    for (int i = t; i < NB; i += 256) {
        int idx = i * NBLK_E + b;
        base_s[i] = hs_scan[idx] + tops[idx >> 10];
        cur_s[i] = 0;
    }
    __syncthreads();
    for (int e = e0 + t; e < e1; e += 256) {
        int d = dst[e];
        int bk = d >> 7;
        int pos = base_s[bk] + atomicAdd(&cur_s[bk], 1);
        pairs[pos] = ((unsigned)src[e] << 7) | (unsigned)(d & 127);
    }
}

// ---- K4: fused bucket sort + gather1 (tops re-derived locally) ----
__global__ __launch_bounds__(512) void fused_gather1_kernel(
    const unsigned short* __restrict__ y1,
    const unsigned* __restrict__ pairs,
    const int* __restrict__ hs_scan, const int* __restrict__ blk2,
    int* __restrict__ row_ptr, int* __restrict__ sorted_src,
    float* __restrict__ h1)
{
    __shared__ int slist[CAP];
    __shared__ int hist[BK];
    __shared__ int sc[BK];
    __shared__ int cur[BK];
    __shared__ int tops[256];
    const int b = blockIdx.x;
    const int t = threadIdx.x;
    const int lane = t & 63;
    const int wv = t >> 6;            // 0..7
    const int g = lane >> 3;          // 8 edge slots
    const int fl = lane & 7;          // uint4 chunk of the 128 B row

    local_tops_scan(blk2, tops, t);

    const int i0 = b * NBLK_E;
    const int start = hs_scan[i0] + tops[i0 >> 10];
    const int end = (b == NB - 1) ? N_EDGES
                    : hs_scan[i0 + NBLK_E] + tops[(i0 + NBLK_E) >> 10];
    const int cnt = end - start;
    const int node0 = b * BK;

    if (t < BK) hist[t] = 0;
    __syncthreads();
    for (int e = start + t; e < end; e += 512)
        atomicAdd(&hist[pairs[e] & 127u], 1);
    __syncthreads();

    int v = (t < BK) ? hist[t] : 0;
    if (t < BK) sc[t] = v;
    __syncthreads();
    for (int off = 1; off < BK; off <<= 1) {
        int tv = (t >= off && t < BK) ? sc[t - off] : 0;
        __syncthreads();
        if (t < BK) sc[t] += tv;
        __syncthreads();
    }
    const int excl = (t < BK) ? sc[t] - v : 0;
    if (t < BK && node0 + t < N_NODES) row_ptr[node0 + t] = start + excl;
    if (b == NB - 1 && t == 0) row_ptr[N_NODES] = N_EDGES;
    if (t < BK) cur[t] = excl;
    __syncthreads();

    if (cnt <= CAP) {
        for (int e = start + t; e < end; e += 512) {
            unsigned u = pairs[e];
            int p = atomicAdd(&cur[u & 127u], 1);
            slist[p] = (int)(u >> 7);
        }
        __syncthreads();
        for (int i = t; i < cnt; i += 512)
            sorted_src[start + i] = slist[i];
        for (int m = 0; m < 16; ++m) {
            const int node = wv * 16 + m;
            const int gn = node0 + node;
            if (gn >= N_NODES) break;
            const int o = sc[node] - hist[node];
            const int dg = hist[node];
            float a0 = 0.f, a1 = 0.f, a2 = 0.f, a3 = 0.f;
            float a4 = 0.f, a5 = 0.f, a6 = 0.f, a7 = 0.f;
            for (int base = 0; base < dg; base += 8) {
                const int idx = base + g;
                if (idx < dg) {
                    const int s = slist[o + idx];
                    uint4 raw = ((const uint4*)(y1 + (size_t)s * 64))[fl];
                    a0 += __uint_as_float(raw.x << 16);
                    a1 += __uint_as_float(raw.x & 0xffff0000u);
                    a2 += __uint_as_float(raw.y << 16);
                    a3 += __uint_as_float(raw.y & 0xffff0000u);
                    a4 += __uint_as_float(raw.z << 16);
                    a5 += __uint_as_float(raw.z & 0xffff0000u);
                    a6 += __uint_as_float(raw.w << 16);
                    a7 += __uint_as_float(raw.w & 0xffff0000u);
                }
            }
#pragma unroll
            for (int d = 8; d <= 32; d <<= 1) {
                a0 += __shfl_xor(a0, d); a1 += __shfl_xor(a1, d);
                a2 += __shfl_xor(a2, d); a3 += __shfl_xor(a3, d);
                a4 += __shfl_xor(a4, d); a5 += __shfl_xor(a5, d);
                a6 += __shfl_xor(a6, d); a7 += __shfl_xor(a7, d);
            }
            const float invd = 1.0f / (float)max(dg, 1);
            if (g == 0) {
                float4* hp = (float4*)(h1 + (size_t)gn * 64);
                float4 z0 = hp[fl * 2];
                float4 z1v = hp[fl * 2 + 1];
                hp[fl * 2] = make_float4(fmaxf(z0.x + a0 * invd, 0.f),
                                         fmaxf(z0.y + a1 * invd, 0.f),
                                         fmaxf(z0.z + a2 * invd, 0.f),
                                         fmaxf(z0.w + a3 * invd, 0.f));
                hp[fl * 2 + 1] = make_float4(fmaxf(z1v.x + a4 * invd, 0.f),
                                             fmaxf(z1v.y + a5 * invd, 0.f),
                                             fmaxf(z1v.z + a6 * invd, 0.f),
                                             fmaxf(z1v.w + a7 * invd, 0.f));
            }
        }
    } else {
        // fallback (statistically unreachable): global two-phase sort + gather
        if (t < BK) cur[t] = start + excl;
        __syncthreads();
        for (int e = start + t; e < end; e += 512) {
            unsigned u = pairs[e];
            int p = atomicAdd(&cur[u & 127u], 1);
            sorted_src[p] = (int)(u >> 7);
        }
        __syncthreads();
        for (int m = 0; m < 16; ++m) {
            const int node = wv * 16 + m;
            const int gn = node0 + node;
            if (gn >= N_NODES) break;
            const int o = start + sc[node] - hist[node];
            const int dg = hist[node];
            float a0 = 0.f, a1 = 0.f, a2 = 0.f, a3 = 0.f;
            float a4 = 0.f, a5 = 0.f, a6 = 0.f, a7 = 0.f;
            for (int base = 0; base < dg; base += 8) {
                const int idx = base + g;
                if (idx < dg) {
                    const int s = sorted_src[o + idx];
                    uint4 raw = ((const uint4*)(y1 + (size_t)s * 64))[fl];
                    a0 += __uint_as_float(raw.x << 16);
                    a1 += __uint_as_float(raw.x & 0xffff0000u);
                    a2 += __uint_as_float(raw.y << 16);
                    a3 += __uint_as_float(raw.y & 0xffff0000u);
                    a4 += __uint_as_float(raw.z << 16);
                    a5 += __uint_as_float(raw.z & 0xffff0000u);
                    a6 += __uint_as_float(raw.w << 16);
                    a7 += __uint_as_float(raw.w & 0xffff0000u);
                }
            }
#pragma unroll
            for (int d = 8; d <= 32; d <<= 1) {
                a0 += __shfl_xor(a0, d); a1 += __shfl_xor(a1, d);
                a2 += __shfl_xor(a2, d); a3 += __shfl_xor(a3, d);
                a4 += __shfl_xor(a4, d); a5 += __shfl_xor(a5, d);
                a6 += __shfl_xor(a6, d); a7 += __shfl_xor(a7, d);
            }
            const float invd = 1.0f / (float)max(dg, 1);
            if (g == 0) {
                float4* hp = (float4*)(h1 + (size_t)gn * 64);
                float4 z0 = hp[fl * 2];
                float4 z1v = hp[fl * 2 + 1];
                hp[fl * 2] = make_float4(fmaxf(z0.x + a0 * invd, 0.f),
                                         fmaxf(z0.y + a1 * invd, 0.f),
                                         fmaxf(z0.z + a2 * invd, 0.f),
                                         fmaxf(z0.w + a3 * invd, 0.f));
                hp[fl * 2 + 1] = make_float4(fmaxf(z1v.x + a4 * invd, 0.f),
                                             fmaxf(z1v.y + a5 * invd, 0.f),
                                             fmaxf(z1v.z + a6 * invd, 0.f),
                                             fmaxf(z1v.w + a7 * invd, 0.f));
            }
        }
    }
}

// ---- K5: dense2 (weights-in-lanes) ----
__global__ __launch_bounds__(256) void dense2_kernel(
    const float* __restrict__ h1,
    const float* __restrict__ Wn, const float* __restrict__ Ws,
    const float* __restrict__ b,
    float* __restrict__ y2, float* __restrict__ out)
{
    __shared__ float sx[32 * 68];
    const int t = threadIdx.x;
    const int w = t >> 6;
    const int lane = t & 63;
    const int half = w >> 1;
    const int nsub = (w & 1) * 16;
    const int j = lane & 15;
    const int g = lane >> 4;
    const int chunk = blockIdx.x * 32;

    {
        const float4* gx = (const float4*)(h1 + (size_t)chunk * 64);
        float4* sx4 = (float4*)sx;
        int r0 = t >> 4, c0 = t & 15;
        sx4[r0 * 17 + c0] = gx[t];
        sx4[(r0 + 16) * 17 + c0] = gx[t + 256];
    }

    const float* W = half ? Ws : Wn;
    float wr[64];
#pragma unroll
    for (int k = 0; k < 64; ++k) wr[k] = W[k * 16 + j];
    const float bj = half ? b[j] : 0.f;

    __syncthreads();

#pragma unroll 1
    for (int q = 0; q < 4; ++q) {
        const int node = nsub + q * 4 + g;
        const float4* xr = (const float4*)(sx + node * 68);
        float a0 = 0.f, a1 = 0.f, a2 = 0.f, a3 = 0.f;
#pragma unroll
        for (int k4 = 0; k4 < 16; ++k4) {
            float4 v = xr[k4];
            a0 += v.x * wr[4 * k4 + 0];
            a1 += v.y * wr[4 * k4 + 1];
            a2 += v.z * wr[4 * k4 + 2];
            a3 += v.w * wr[4 * k4 + 3];
        }
        const float o = (a0 + a1) + (a2 + a3) + bj;
        const size_t gn = (size_t)(chunk + node);
        if (half) out[gn * 16 + j] = o;
        else      y2[gn * 16 + j] = o;
    }
}

// ---- K6: gather2 ----
__global__ __launch_bounds__(256) void gather2_kernel(
    const float* __restrict__ y2,
    const int* __restrict__ row_ptr,
    const int* __restrict__ sorted_src,
    float* __restrict__ out)
{
    const int w = threadIdx.x >> 6;
    const int lane = threadIdx.x & 63;
    const int n = blockIdx.x * 4 + w;
    const int group = lane >> 2;
    const int fl = lane & 3;

    const int start = row_ptr[n];
    const int deg = row_ptr[n + 1] - start;

    float4 acc = make_float4(0.f, 0.f, 0.f, 0.f);
    for (int base = 0; base < deg; base += 64) {
        const int m = min(64, deg - base);
        int eid = 0;
        if (lane < m) eid = sorted_src[start + base + lane];
        for (int jj = 0; jj < m; jj += 16) {
            const int idx = jj + group;
            const int s = __shfl(eid, idx);
            if (idx < m) {
                float4 v = ((const float4*)(y2 + (size_t)s * 16))[fl];
                acc.x += v.x; acc.y += v.y; acc.z += v.z; acc.w += v.w;
            }
        }
    }
#pragma unroll
    for (int d = 4; d <= 32; d <<= 1) {
        acc.x += __shfl_xor(acc.x, d); acc.y += __shfl_xor(acc.y, d);
        acc.z += __shfl_xor(acc.z, d); acc.w += __shfl_xor(acc.w, d);
    }
    const float invd = 1.0f / (float)max(deg, 1);
    if (lane < 4) {
        float4* op = (float4*)(out + (size_t)n * 16);
        float4 z = op[fl];
        op[fl] = make_float4(z.x + acc.x * invd, z.y + acc.y * invd,
                             z.z + acc.z * invd, z.w + acc.w * invd);
    }
}

extern "C" void kernel_launch(void* const* d_in, const int* in_sizes, int n_in,
                              void* d_out, int out_size, void* d_ws, size_t ws_size,
                              hipStream_t stream) {
    const float* x   = (const float*)d_in[0];
    const int*   src = (const int*)d_in[1];
    const int*   dst = (const int*)d_in[2];
    const float* W1s = (const float*)d_in[3];
    const float* W1n = (const float*)d_in[4];
    const float* b1  = (const float*)d_in[5];
    const float* W2s = (const float*)d_in[6];
    const float* W2n = (const float*)d_in[7];
    const float* b2  = (const float*)d_in[8];
    float* out = (float*)d_out;

    char* ws = (char*)d_ws;
    int* row_ptr    = (int*)(ws + OFF_ROWPTR);
    int* hist_g     = (int*)(ws + OFF_HISTG);
    int* hs_scan    = (int*)(ws + OFF_HSCAN);
    int* blk2       = (int*)(ws + OFF_BLK2);
    unsigned* pairs = (unsigned*)(ws + OFF_PAIRS);
    int* sorted_src = (int*)(ws + OFF_SORTED);
    unsigned short* y1 = (unsigned short*)(ws + OFF_Y1);
    float* y2       = (float*)(ws + OFF_Y1);   // reuses y1 space after fused_gather1
    float* h1       = (float*)(ws + OFF_H1);

    // K1: hist (293 blocks) + dense1 (3125 blocks) overlapped in one launch
    hist_dense1_kernel<<<NBLK_E + ND1, 256, 0, stream>>>(
        dst, hist_g, x, W1n, W1s, b1, y1, h1);
    // K2: block-local scans; blk2 = raw block sums
    scan2_blocks_kernel<<<NSB2, 1024, 0, stream>>>(hist_g, hs_scan, blk2);
    // K3: deterministic pair scatter (local tops scan)
    pair_scatter_kernel<<<NBLK_E, 256, 0, stream>>>(src, dst, hs_scan, blk2, pairs);
    // K4: fused bucket sort + gather1 (also emits row_ptr/sorted_src)
    fused_gather1_kernel<<<NB, 512, 0, stream>>>(y1, pairs, hs_scan, blk2,
                                                 row_ptr, sorted_src, h1);
    // K5/K6: layer 2
    dense2_kernel<<<ND1, 256, 0, stream>>>(h1, W2n, W2s, b2, y2, out);
    gather2_kernel<<<N_NODES / 4, 256, 0, stream>>>(y2, row_ptr, sorted_src, out);
}

// Round 13
// 228.029 us; speedup vs baseline: 1.0849x; 1.0564x over previous
//
#include <hip/hip_runtime.h>

#define N_NODES 100000
#define N_EDGES 1200000
#define BK 128                    // nodes per bucket
#define NB 782                    // ceil(100000/128)
#define CHUNK_E 4096
#define NBLK_E 293                // ceil(N_EDGES / CHUNK_E)
#define TOT_H (NB * NBLK_E)       // 229126
#define NSB2 ((TOT_H + 1023) / 1024)   // 224
#define CAP 4096                  // LDS edge-list capacity (expected ~1535 +- 39)
#define ND1 3125                  // dense1 blocks (32 nodes each)

// Workspace layout (bytes), ~50.2 MB:
#define OFF_ROWPTR 0
#define OFF_HISTG  400896
#define OFF_HSCAN  1317632
#define OFF_BLK2   2234368
#define OFF_PAIRS  2235392
#define OFF_SORTED 7035392
#define OFF_Y1     11835392
#define OFF_H1     24635392

__device__ __forceinline__ unsigned short f2bf(float f) {
    unsigned u = __float_as_uint(f);
    unsigned r = (u + 0x7fffu + ((u >> 16) & 1u)) >> 16;   // RNE
    return (unsigned short)r;
}

// ---- K1: chunk_hist (blocks 0..292) + dense1 (blocks 293..3417) fused ----
__global__ __launch_bounds__(256) void hist_dense1_kernel(
    const int* __restrict__ dst, int* __restrict__ hist_g,
    const float* __restrict__ x,
    const float* __restrict__ Wn, const float* __restrict__ Ws,
    const float* __restrict__ b,
    unsigned short* __restrict__ y1, float* __restrict__ z1)
{
    __shared__ float sx[32 * 64];   // 8 KB; hist part reuses as int h[NB]
    const int t = threadIdx.x;

    if (blockIdx.x < NBLK_E) {
        int* h = (int*)sx;
        const int e0 = blockIdx.x * CHUNK_E;
        const int e1 = min(e0 + CHUNK_E, N_EDGES);
        for (int i = t; i < NB; i += 256) h[i] = 0;
        __syncthreads();
        for (int e = e0 + t; e < e1; e += 256)
            atomicAdd(&h[dst[e] >> 7], 1);
        __syncthreads();
        for (int i = t; i < NB; i += 256)
            hist_g[i * NBLK_E + blockIdx.x] = h[i];
        return;
    }

    const int bid = blockIdx.x - NBLK_E;
    const int w = t >> 6;
    const int lane = t & 63;
    const int half = w >> 1;
    const int nsub = (w & 1) * 16;
    const int chunk = bid * 32;

    {
        const float4* gx = (const float4*)(x + (size_t)chunk * 64);
        float4* sx4 = (float4*)sx;
        sx4[t] = gx[t];
        sx4[t + 256] = gx[t + 256];
    }

    const float* W = half ? Ws : Wn;
    float wr[64];
#pragma unroll
    for (int k = 0; k < 64; ++k) wr[k] = W[k * 64 + lane];
    const float bj = half ? b[lane] : 0.f;

    __syncthreads();

#pragma unroll 1
    for (int m = 0; m < 16; ++m) {
        const int node = nsub + m;
        const float4* xr = (const float4*)(sx + node * 64);
        float a0 = 0.f, a1 = 0.f, a2 = 0.f, a3 = 0.f;
#pragma unroll
        for (int k4 = 0; k4 < 16; ++k4) {
            float4 v = xr[k4];
            a0 += v.x * wr[4 * k4 + 0];
            a1 += v.y * wr[4 * k4 + 1];
            a2 += v.z * wr[4 * k4 + 2];
            a3 += v.w * wr[4 * k4 + 3];
        }
        const float o = (a0 + a1) + (a2 + a3) + bj;
        const size_t gn = (size_t)(chunk + node);
        if (half) z1[gn * 64 + lane] = o;
        else      y1[gn * 64 + lane] = f2bf(o);
    }
}

// ---- K2: block-local scan of hist_g; blk2 holds RAW block sums ----
__global__ __launch_bounds__(1024) void scan2_blocks_kernel(
    const int* __restrict__ hist_g, int* __restrict__ hs_scan, int* __restrict__ blk2)
{
    __shared__ int s[1024];
    int i = blockIdx.x * 1024 + threadIdx.x;
    int v = (i < TOT_H) ? hist_g[i] : 0;
    s[threadIdx.x] = v;
    __syncthreads();
    for (int off = 1; off < 1024; off <<= 1) {
        int t = (threadIdx.x >= off) ? s[threadIdx.x - off] : 0;
        __syncthreads();
        s[threadIdx.x] += t;
        __syncthreads();
    }
    if (i < TOT_H) hs_scan[i] = s[threadIdx.x] - v;
    if (threadIdx.x == 1023) blk2[blockIdx.x] = s[1023];
}

// local exclusive scan of blk2 (NSB2<=256) into tops[]; call with >=256 threads
__device__ __forceinline__ void local_tops_scan(const int* blk2, int* tops, int t)
{
    if (t < 256) {
        int v = (t < NSB2) ? blk2[t] : 0;
        tops[t] = v;
    }
    __syncthreads();
    for (int off = 1; off < 256; off <<= 1) {
        int tv = (t >= off && t < 256) ? tops[t - off] : 0;
        __syncthreads();
        if (t < 256) tops[t] += tv;
        __syncthreads();
    }
    int ex = 0;
    if (t < 256) ex = tops[t] - ((t < NSB2) ? blk2[t] : 0);
    __syncthreads();
    if (t < 256) tops[t] = ex;
    __syncthreads();
}

// ---- K3: deterministic pair scatter (tops re-derived locally) ----
__global__ __launch_bounds__(256) void pair_scatter_kernel(
    const int* __restrict__ src, const int* __restrict__ dst,
    const int* __restrict__ hs_scan, const int* __restrict__ blk2,
    unsigned* __restrict__ pairs)
{
    __shared__ int base_s[NB];
    __shared__ int cur_s[NB];
    __shared__ int tops[256];
    const int b = blockIdx.x;
    const int t = threadIdx.x;
    const int e0 = b * CHUNK_E;
    const int e1 = min(e0 + CHUNK_E, N_EDGES);

    local_tops_scan(blk2, tops, t);

    for (int i = t; i < NB; i += 256) {
        int idx = i * NBLK_E + b;
        base_s[i] = hs_scan[idx] + tops[idx >> 10];
        cur_s[i] = 0;
    }
    __syncthreads();
    for (int e = e0 + t; e < e1; e += 256) {
        int d = dst[e];
        int bk = d >> 7;
        int pos = base_s[bk] + atomicAdd(&cur_s[bk], 1);
        pairs[pos] = ((unsigned)src[e] << 7) | (unsigned)(d & 127);
    }
}

// ---- K4: fused bucket sort + gather1 ----
__global__ __launch_bounds__(512) void fused_gather1_kernel(
    const unsigned short* __restrict__ y1,
    const unsigned* __restrict__ pairs,
    const int* __restrict__ hs_scan, const int* __restrict__ blk2,
    int* __restrict__ row_ptr, int* __restrict__ sorted_src,
    float* __restrict__ h1)
{
    __shared__ int slist[CAP];
    __shared__ int hist[BK];
    __shared__ int sc[BK];
    __shared__ int cur[BK];
    __shared__ int tops[256];
    const int b = blockIdx.x;
    const int t = threadIdx.x;
    const int lane = t & 63;
    const int wv = t >> 6;            // 0..7
    const int g = lane >> 3;          // 8 edge slots
    const int fl = lane & 7;          // uint4 chunk of the 128 B row

    local_tops_scan(blk2, tops, t);

    const int i0 = b * NBLK_E;
    const int start = hs_scan[i0] + tops[i0 >> 10];
    const int end = (b == NB - 1) ? N_EDGES
                    : hs_scan[i0 + NBLK_E] + tops[(i0 + NBLK_E) >> 10];
    const int cnt = end - start;
    const int node0 = b * BK;

    if (t < BK) hist[t] = 0;
    __syncthreads();
    for (int e = start + t; e < end; e += 512)
        atomicAdd(&hist[pairs[e] & 127u], 1);
    __syncthreads();

    int v = (t < BK) ? hist[t] : 0;
    if (t < BK) sc[t] = v;
    __syncthreads();
    for (int off = 1; off < BK; off <<= 1) {
        int tv = (t >= off && t < BK) ? sc[t - off] : 0;
        __syncthreads();
        if (t < BK) sc[t] += tv;
        __syncthreads();
    }
    const int excl = (t < BK) ? sc[t] - v : 0;
    if (t < BK && node0 + t < N_NODES) row_ptr[node0 + t] = start + excl;
    if (b == NB - 1 && t == 0) row_ptr[N_NODES] = N_EDGES;
    if (t < BK) cur[t] = excl;
    __syncthreads();

    if (cnt <= CAP) {
        for (int e = start + t; e < end; e += 512) {
            unsigned u = pairs[e];
            int p = atomicAdd(&cur[u & 127u], 1);
            slist[p] = (int)(u >> 7);
        }
        __syncthreads();
        for (int i = t; i < cnt; i += 512)
            sorted_src[start + i] = slist[i];
        for (int m = 0; m < 16; ++m) {
            const int node = wv * 16 + m;
            const int gn = node0 + node;
            if (gn >= N_NODES) break;
            const int o = sc[node] - hist[node];
            const int dg = hist[node];
            float a0 = 0.f, a1 = 0.f, a2 = 0.f, a3 = 0.f;
            float a4 = 0.f, a5 = 0.f, a6 = 0.f, a7 = 0.f;
            for (int base = 0; base < dg; base += 8) {
                const int idx = base + g;
                if (idx < dg) {
                    const int s = slist[o + idx];
                    uint4 raw = ((const uint4*)(y1 + (size_t)s * 64))[fl];
                    a0 += __uint_as_float(raw.x << 16);
                    a1 += __uint_as_float(raw.x & 0xffff0000u);
                    a2 += __uint_as_float(raw.y << 16);
                    a3 += __uint_as_float(raw.y & 0xffff0000u);
                    a4 += __uint_as_float(raw.z << 16);
                    a5 += __uint_as_float(raw.z & 0xffff0000u);
                    a6 += __uint_as_float(raw.w << 16);
                    a7 += __uint_as_float(raw.w & 0xffff0000u);
                }
            }
#pragma unroll
            for (int d = 8; d <= 32; d <<= 1) {
                a0 += __shfl_xor(a0, d); a1 += __shfl_xor(a1, d);
                a2 += __shfl_xor(a2, d); a3 += __shfl_xor(a3, d);
                a4 += __shfl_xor(a4, d); a5 += __shfl_xor(a5, d);
                a6 += __shfl_xor(a6, d); a7 += __shfl_xor(a7, d);
            }
            const float invd = 1.0f / (float)max(dg, 1);
            if (g == 0) {
                float4* hp = (float4*)(h1 + (size_t)gn * 64);
                float4 z0 = hp[fl * 2];
                float4 z1v = hp[fl * 2 + 1];
                hp[fl * 2] = make_float4(fmaxf(z0.x + a0 * invd, 0.f),
                                         fmaxf(z0.y + a1 * invd, 0.f),
                                         fmaxf(z0.z + a2 * invd, 0.f),
                                         fmaxf(z0.w + a3 * invd, 0.f));
                hp[fl * 2 + 1] = make_float4(fmaxf(z1v.x + a4 * invd, 0.f),
                                             fmaxf(z1v.y + a5 * invd, 0.f),
                                             fmaxf(z1v.z + a6 * invd, 0.f),
                                             fmaxf(z1v.w + a7 * invd, 0.f));
            }
        }
    } else {
        // fallback (statistically unreachable): global two-phase sort + gather
        if (t < BK) cur[t] = start + excl;
        __syncthreads();
        for (int e = start + t; e < end; e += 512) {
            unsigned u = pairs[e];
            int p = atomicAdd(&cur[u & 127u], 1);
            sorted_src[p] = (int)(u >> 7);
        }
        __syncthreads();
        for (int m = 0; m < 16; ++m) {
            const int node = wv * 16 + m;
            const int gn = node0 + node;
            if (gn >= N_NODES) break;
            const int o = start + sc[node] - hist[node];
            const int dg = hist[node];
            float a0 = 0.f, a1 = 0.f, a2 = 0.f, a3 = 0.f;
            float a4 = 0.f, a5 = 0.f, a6 = 0.f, a7 = 0.f;
            for (int base = 0; base < dg; base += 8) {
                const int idx = base + g;
                if (idx < dg) {
                    const int s = sorted_src[o + idx];
                    uint4 raw = ((const uint4*)(y1 + (size_t)s * 64))[fl];
                    a0 += __uint_as_float(raw.x << 16);
                    a1 += __uint_as_float(raw.x & 0xffff0000u);
                    a2 += __uint_as_float(raw.y << 16);
                    a3 += __uint_as_float(raw.y & 0xffff0000u);
                    a4 += __uint_as_float(raw.z << 16);
                    a5 += __uint_as_float(raw.z & 0xffff0000u);
                    a6 += __uint_as_float(raw.w << 16);
                    a7 += __uint_as_float(raw.w & 0xffff0000u);
                }
            }
#pragma unroll
            for (int d = 8; d <= 32; d <<= 1) {
                a0 += __shfl_xor(a0, d); a1 += __shfl_xor(a1, d);
                a2 += __shfl_xor(a2, d); a3 += __shfl_xor(a3, d);
                a4 += __shfl_xor(a4, d); a5 += __shfl_xor(a5, d);
                a6 += __shfl_xor(a6, d); a7 += __shfl_xor(a7, d);
            }
            const float invd = 1.0f / (float)max(dg, 1);
            if (g == 0) {
                float4* hp = (float4*)(h1 + (size_t)gn * 64);
                float4 z0 = hp[fl * 2];
                float4 z1v = hp[fl * 2 + 1];
                hp[fl * 2] = make_float4(fmaxf(z0.x + a0 * invd, 0.f),
                                         fmaxf(z0.y + a1 * invd, 0.f),
                                         fmaxf(z0.z + a2 * invd, 0.f),
                                         fmaxf(z0.w + a3 * invd, 0.f));
                hp[fl * 2 + 1] = make_float4(fmaxf(z1v.x + a4 * invd, 0.f),
                                             fmaxf(z1v.y + a5 * invd, 0.f),
                                             fmaxf(z1v.z + a6 * invd, 0.f),
                                             fmaxf(z1v.w + a7 * invd, 0.f));
            }
        }
    }
}

// ---- K5: dense2 (weights-in-lanes) ----
__global__ __launch_bounds__(256) void dense2_kernel(
    const float* __restrict__ h1,
    const float* __restrict__ Wn, const float* __restrict__ Ws,
    const float* __restrict__ b,
    float* __restrict__ y2, float* __restrict__ out)
{
    __shared__ float sx[32 * 68];
    const int t = threadIdx.x;
    const int w = t >> 6;
    const int lane = t & 63;
    const int half = w >> 1;
    const int nsub = (w & 1) * 16;
    const int j = lane & 15;
    const int g = lane >> 4;
    const int chunk = blockIdx.x * 32;

    {
        const float4* gx = (const float4*)(h1 + (size_t)chunk * 64);
        float4* sx4 = (float4*)sx;
        int r0 = t >> 4, c0 = t & 15;
        sx4[r0 * 17 + c0] = gx[t];
        sx4[(r0 + 16) * 17 + c0] = gx[t + 256];
    }

    const float* W = half ? Ws : Wn;
    float wr[64];
#pragma unroll
    for (int k = 0; k < 64; ++k) wr[k] = W[k * 16 + j];
    const float bj = half ? b[j] : 0.f;

    __syncthreads();

#pragma unroll 1
    for (int q = 0; q < 4; ++q) {
        const int node = nsub + q * 4 + g;
        const float4* xr = (const float4*)(sx + node * 68);
        float a0 = 0.f, a1 = 0.f, a2 = 0.f, a3 = 0.f;
#pragma unroll
        for (int k4 = 0; k4 < 16; ++k4) {
            float4 v = xr[k4];
            a0 += v.x * wr[4 * k4 + 0];
            a1 += v.y * wr[4 * k4 + 1];
            a2 += v.z * wr[4 * k4 + 2];
            a3 += v.w * wr[4 * k4 + 3];
        }
        const float o = (a0 + a1) + (a2 + a3) + bj;
        const size_t gn = (size_t)(chunk + node);
        if (half) out[gn * 16 + j] = o;
        else      y2[gn * 16 + j] = o;
    }
}

// ---- K6: gather2 v2 — 4 nodes per wave (16 lanes/node: 4 edge slots x float4)
__global__ __launch_bounds__(256) void gather2_kernel(
    const float* __restrict__ y2,
    const int* __restrict__ row_ptr,
    const int* __restrict__ sorted_src,
    float* __restrict__ out)
{
    const int wv = threadIdx.x >> 6;
    const int lane = threadIdx.x & 63;
    const int sub = lane >> 4;        // node slot 0..3
    const int sl = lane & 15;         // lane within node group
    const int eg = sl >> 2;           // edge slot 0..3
    const int fl = sl & 3;            // float4 chunk of 16-f32 row

    const int n = blockIdx.x * 16 + wv * 4 + sub;   // grid 6250 -> exact
    const int start = row_ptr[n];
    const int deg = row_ptr[n + 1] - start;

    float4 acc = make_float4(0.f, 0.f, 0.f, 0.f);
    for (int base = 0; base < deg; base += 16) {
        int eid = 0;
        if (base + sl < deg) eid = sorted_src[start + base + sl];
        // 4 passes of 4 edges; edge idx = jj + eg, source lane = sub*16 + idx
#pragma unroll
        for (int jj = 0; jj < 16; jj += 4) {
            const int idx = jj + eg;
            const int s = __shfl(eid, sub * 16 + idx);
            if (base + idx < deg) {
                float4 v = ((const float4*)(y2 + (size_t)s * 16))[fl];
                acc.x += v.x; acc.y += v.y; acc.z += v.z; acc.w += v.w;
            }
        }
    }
    // reduce over the 4 edge slots (within each 16-lane node group)
#pragma unroll
    for (int d = 4; d <= 8; d <<= 1) {
        acc.x += __shfl_xor(acc.x, d); acc.y += __shfl_xor(acc.y, d);
        acc.z += __shfl_xor(acc.z, d); acc.w += __shfl_xor(acc.w, d);
    }
    const float invd = 1.0f / (float)max(deg, 1);
    if (eg == 0) {
        float4* op = (float4*)(out + (size_t)n * 16);
        float4 z = op[fl];
        op[fl] = make_float4(z.x + acc.x * invd, z.y + acc.y * invd,
                             z.z + acc.z * invd, z.w + acc.w * invd);
    }
}

extern "C" void kernel_launch(void* const* d_in, const int* in_sizes, int n_in,
                              void* d_out, int out_size, void* d_ws, size_t ws_size,
                              hipStream_t stream) {
    const float* x   = (const float*)d_in[0];
    const int*   src = (const int*)d_in[1];
    const int*   dst = (const int*)d_in[2];
    const float* W1s = (const float*)d_in[3];
    const float* W1n = (const float*)d_in[4];
    const float* b1  = (const float*)d_in[5];
    const float* W2s = (const float*)d_in[6];
    const float* W2n = (const float*)d_in[7];
    const float* b2  = (const float*)d_in[8];
    float* out = (float*)d_out;

    char* ws = (char*)d_ws;
    int* row_ptr    = (int*)(ws + OFF_ROWPTR);
    int* hist_g     = (int*)(ws + OFF_HISTG);
    int* hs_scan    = (int*)(ws + OFF_HSCAN);
    int* blk2       = (int*)(ws + OFF_BLK2);
    unsigned* pairs = (unsigned*)(ws + OFF_PAIRS);
    int* sorted_src = (int*)(ws + OFF_SORTED);
    unsigned short* y1 = (unsigned short*)(ws + OFF_Y1);
    float* y2       = (float*)(ws + OFF_Y1);   // reuses y1 space after fused_gather1
    float* h1       = (float*)(ws + OFF_H1);

    hist_dense1_kernel<<<NBLK_E + ND1, 256, 0, stream>>>(
        dst, hist_g, x, W1n, W1s, b1, y1, h1);
    scan2_blocks_kernel<<<NSB2, 1024, 0, stream>>>(hist_g, hs_scan, blk2);
    pair_scatter_kernel<<<NBLK_E, 256, 0, stream>>>(src, dst, hs_scan, blk2, pairs);
    fused_gather1_kernel<<<NB, 512, 0, stream>>>(y1, pairs, hs_scan, blk2,
                                                 row_ptr, sorted_src, h1);
    dense2_kernel<<<ND1, 256, 0, stream>>>(h1, W2n, W2s, b2, y2, out);
    gather2_kernel<<<N_NODES / 16, 256, 0, stream>>>(y2, row_ptr, sorted_src, out);
}